// Round 4
// baseline (295.308 us; speedup 1.0000x reference)
//
#include <hip/hip_runtime.h>

// WaveletPatcher: 3-level a-trous db4 SWT (periodic) + overlapping patch extract.
// x: (64, 4096, 32) f32  ->  out: (64*511, 32*4, 16) f32
//   A_{l+1}[t] = sum_j LO[j] * A_l[(t + (4-j)*d) & 4095],  d = 2^l
// c=0:A3, 1:D3, 2:D2, 3:D1.  out[(b*511+p)*2048 + n*64 + c*16 + j], t = 8p+j.
//
// History: R3 staged 5-phase 290us; R4 2x blocks/CU (halved work/block) 291us;
// R5 scattered 16B stores 392us (partial-line RMW -- NEVER); R6 register
// cascade (this structure) 289us. R4+R6 nulls => not LDS/barrier-bound.
// R7 isolates OCCUPANCY with work/block held constant (the R4 confound):
//  - __launch_bounds__(256,3): >=3 blocks/CU (12 waves) vs R6's possible 2;
//    LDS 39KB allows 4 if VGPR <= 128. Peak live ~70 floats -> no spill risk.
//  - XCD swizzle: blk low 3 bits -> b-group, so each XCD (round-robin dispatch)
//    touches only 8 b-series = 4MB input = its L2; halo re-reads become L2 hits.
// If this is neutral too, the kernel is at its structural floor (~55-70us) and
// the residual vs 289 total is harness reset traffic => roofline.

#define NTHREADS 256
#define T_MASK   4095

#define S_ST 76                      // stage stride (trel 0..71, +4 pad)
#define ST_C 2436                    // 32*76 + 4 (bank de-phase between c)
#define LDS_FLOATS (4 * ST_C)        // 9744 floats = 38976 B

__device__ __constant__ float c_lo[8] = {
    -0.010597401784997278f, 0.032883011666982945f, 0.030841381835986965f,
    -0.18703481171888114f, -0.02798376941698385f, 0.6308807679295904f,
    0.7148465705525415f,   0.23037781330885523f};
__device__ __constant__ float c_hi[8] = {
    -0.23037781330885523f, 0.7148465705525415f, -0.6308807679295904f,
    -0.02798376941698385f, 0.18703481171888114f, 0.030841381835986965f,
    -0.032883011666982945f, -0.010597401784997278f};

__global__ __launch_bounds__(NTHREADS, 3) void swt_patch(const float* __restrict__ x,
                                                         float* __restrict__ out) {
    __shared__ float lds[LDS_FLOATS];

    const int blk = blockIdx.x;        // 0..4095
    // XCD-aware remap (bijective on low 6 bits): XCD ~ blk&7 -> b-group of 8.
    const int b   = ((blk & 7) << 3) | ((blk >> 3) & 7);   // 0..63
    const int cid = blk >> 6;          // chunk id (owns t = T0 .. T0+63)
    const int T0  = cid << 6;
    const int p0  = cid << 3;          // first patch index (8 per chunk)
    const int tid = threadIdx.x;
    const int n   = tid & 31;          // series (lane dim -> coalesced loads)
    const int s   = tid >> 5;          // octet id 0..7
    const int t0  = 9 * s;             // trel base; outputs trel t0..t0+8

    const float* xb = x + (size_t)b * (4096 * 32) + n;

    // ---- load x window trel [t0-21, t0+36] (58 values) into registers ----
    // lane = n: each load is a coalesced 128B line per s-half-wave.
    float xw[58];
    if (cid != 0 && cid != 63) {       // uniform fast path: no wrap possible
        const float* xp = xb + (size_t)(T0 + t0 - 21) * 32;
#pragma unroll
        for (int i = 0; i < 58; ++i) xw[i] = xp[(size_t)i * 32];
    } else {
#pragma unroll
        for (int i = 0; i < 58; ++i) {
            const int t = (T0 + t0 - 21 + i) & T_MASK;
            xw[i] = xb[(size_t)t * 32];
        }
    }

    // ---- D1 (c=3): trel t0+m, tap j -> xw[m+25-j]; stage immediately ----
    {
        float d1[9];
#pragma unroll
        for (int m = 0; m < 9; ++m) {
            float sd = 0.f;
#pragma unroll
            for (int j = 0; j < 8; ++j) sd = fmaf(c_hi[j], xw[m + 25 - j], sd);
            d1[m] = sd;
        }
#pragma unroll
        for (int m = 0; m < 9; ++m) lds[3 * ST_C + n * S_ST + t0 + m] = d1[m];
    }

    // ---- A1[k], k=0..50 (trel t0-18+k): tap j -> xw[k+7-j]; xw dies rolling ----
    float a1[51];
#pragma unroll
    for (int k = 0; k < 51; ++k) {
        float sa = 0.f;
#pragma unroll
        for (int j = 0; j < 8; ++j) sa = fmaf(c_lo[j], xw[k + 7 - j], sa);
        a1[k] = sa;
    }

    // ---- D2 (c=2): trel t0+m, tap j -> a1[m+26-2j]; stage immediately ----
    {
        float d2[9];
#pragma unroll
        for (int m = 0; m < 9; ++m) {
            float sd = 0.f;
#pragma unroll
            for (int j = 0; j < 8; ++j) sd = fmaf(c_hi[j], a1[m + 26 - 2 * j], sd);
            d2[m] = sd;
        }
#pragma unroll
        for (int m = 0; m < 9; ++m) lds[2 * ST_C + n * S_ST + t0 + m] = d2[m];
    }

    // ---- A2[m2], m2=0..36 (trel t0-12+m2): tap j -> a1[m2+14-2j]; a1 dies rolling ----
    float a2[37];
#pragma unroll
    for (int m2 = 0; m2 < 37; ++m2) {
        float sa = 0.f;
#pragma unroll
        for (int j = 0; j < 8; ++j) sa = fmaf(c_lo[j], a1[m2 + 14 - 2 * j], sa);
        a2[m2] = sa;
    }

    // ---- A3 (c=0) + D3 (c=1): trel t0+m, tap j -> a2[m+28-4j]; stage ----
#pragma unroll
    for (int m = 0; m < 9; ++m) {
        float sa = 0.f, sd = 0.f;
#pragma unroll
        for (int j = 0; j < 8; ++j) {
            const float v = a2[m + 28 - 4 * j];
            sa = fmaf(c_lo[j], v, sa);
            sd = fmaf(c_hi[j], v, sd);
        }
        lds[0 * ST_C + n * S_ST + t0 + m] = sa;
        lds[1 * ST_C + n * S_ST + t0 + m] = sd;
    }
    __syncthreads();

    // ---- store: 8 patches = ONE contiguous 64KB region, float4 streaming (R3-proven) ----
    // region float4 idx e4: p_local = e4>>9, n = (e4>>4)&31, c = (e4>>2)&3, jq = e4&3
    float4* out4 = (float4*)(out + ((size_t)b * 511 + p0) * 2048);
#pragma unroll
    for (int it = 0; it < 16; ++it) {
        const int e4 = tid + it * NTHREADS;            // 0..4095
        const int p_local = e4 >> 9;
        if (p0 + p_local < 511) {
            const int nn = (e4 >> 4) & 31;
            const int c  = (e4 >> 2) & 3;
            const int trel = 8 * p_local + 4 * (e4 & 3);
            out4[e4] = *(const float4*)&lds[c * ST_C + nn * S_ST + trel];
        }
    }
}

extern "C" void kernel_launch(void* const* d_in, const int* in_sizes, int n_in,
                              void* d_out, int out_size, void* d_ws, size_t ws_size,
                              hipStream_t stream) {
    const float* x = (const float*)d_in[0];
    float* out = (float*)d_out;
    hipLaunchKernelGGL(swt_patch, dim3(64 * 64), dim3(NTHREADS), 0, stream, x, out);
}